// Round 9
// baseline (1161.406 us; speedup 1.0000x reference)
//
#include <hip/hip_runtime.h>
#include <hip/hip_bf16.h>
#include <hip/hip_fp16.h>

#define N_NODES 100000
#define N_EDGES 1600000
#define HID     64
#define LAYERS  8
#define OUT_DIM 40
#define SCAN_NB 98   // ceil(100000/1024)
#define T0SL4   ((size_t)(N_NODES + 32) * 16)   // elements per t0 quarter-slice (16 feats)
#define NBUK    196      // ceil(100000/512) buckets of 512 nodes
#define BUK_CAP 12000    // avg 8163/bucket -> huge sigma headroom
#define S1_EPB  2048     // edges per bucket1 block (256 thr x 8)
#define AGG_N   64       // nodes per agg block
#define AGG_CAP 3072     // staged csr entries (mean 1024, +64 sigma), 12KB LDS

typedef __attribute__((ext_vector_type(8))) short short8;
typedef __attribute__((ext_vector_type(8))) _Float16 half8;
typedef __attribute__((ext_vector_type(4))) float float4v;

// ---------- runtime environment hedges ----------
// flags[0] = 1 if feature inputs are float32 (else bf16)
// flags[1] = 1 if edge_index is int64 (else int32)
__device__ inline float ldext(const void* p, bool f32, size_t i) {
    return f32 ? ((const float*)p)[i]
               : __bfloat162float(((const __hip_bfloat16*)p)[i]);
}
__device__ inline int load_edge(const void* raw, bool is64, long long idx) {
    return is64 ? (int)((const long long*)raw)[idx] : ((const int*)raw)[idx];
}
__device__ inline unsigned pack_bf16x2(float lo, float hi) {
    union { __hip_bfloat16 b; unsigned short u; } a, b;
    a.b = __float2bfloat16(lo);
    b.b = __float2bfloat16(hi);
    return ((unsigned)b.u << 16) | a.u;
}
__device__ inline unsigned short bf16bits(float v) {
    union { __hip_bfloat16 b; unsigned short u; } a;
    a.b = __float2bfloat16(v);
    return a.u;
}
__device__ inline unsigned short f16bits(float v) {
    union { __half h; unsigned short u; } a;
    a.h = __float2half_rn(v);
    return a.u;
}
__device__ inline __half2 u2h2(unsigned u) {
    union { unsigned u; __half2 h; } x; x.u = u; return x.h;
}
__device__ inline unsigned h22u(__half2 h) {
    union { unsigned u; __half2 h; } x; x.h = h; return x.u;
}

__global__ void detect_kernel(const void* x, const void* ei, int* flags) {
    int t = threadIdx.x;  // 64 threads
    float v = fabsf(__bfloat162float(((const __hip_bfloat16*)x)[t]));
    bool inband = (v >= 0.00390625f && v <= 16.0f);
    unsigned long long m = __ballot(inband);
    if (t == 0) {
        flags[0] = (__popcll(m) < 48) ? 1 : 0;  // fp32 misread as bf16 -> ~33/64 in band
        const int* e32 = (const int*)ei;
        flags[1] = ((e32[1] | e32[3] | e32[5] | e32[7]) == 0) ? 1 : 0;
    }
}

// pack: bias (fp32); W0 as bf16 MFMA B-frags; W1..7 and lwB as f16 MFMA B-frags.
__global__ __launch_bounds__(256) void pack_params_kernel(const void* bs, const void* lin_w,
                                                          const void* W0, const void* Ws,
                                                          const int* __restrict__ flags,
                                                          float* __restrict__ bsf,
                                                          unsigned short* __restrict__ wpack) {
    bool f32 = flags[0] != 0;
    int gid = blockIdx.x * 256 + threadIdx.x;
    int stride = gridDim.x * 256;
    for (int idx = gid; idx < LAYERS * HID; idx += stride) bsf[idx] = ldext(bs, f32, idx);
    // layer 0 W: K=128 (KS=4), 8192 elements, bf16 (A = x is bf16)
    for (int idx = gid; idx < 8192; idx += stride) {
        int j = idx & 7, lane = (idx >> 3) & 63, rest = idx >> 9;
        int ks = rest & 3, ct = rest >> 2;
        int quad = lane >> 4, m = lane & 15;
        wpack[idx] = bf16bits(ldext(W0, f32, (size_t)(ks * 32 + quad * 8 + j) * 64 + ct * 16 + m));
    }
    // layers 1..7 W: K=64 (KS=2), 4096 each, f16 (A = h is f16)
    for (int idx = gid; idx < 7 * 4096; idx += stride) {
        int l = idx >> 12, r = idx & 4095;
        int j = r & 7, lane = (r >> 3) & 63, rest = r >> 9;
        int ks = rest & 1, ct = rest >> 1;
        int quad = lane >> 4, m = lane & 15;
        wpack[8192 + idx] = f16bits(
            ldext(Ws, f32, (size_t)l * 4096 + (size_t)(ks * 32 + quad * 8 + j) * 64 + ct * 16 + m));
    }
    // lwB: 8 layers x 3072 (3 ct x 2 ks x 64 lanes x 8), f16
    for (int idx = gid; idx < LAYERS * 3072; idx += stride) {
        int l = idx / 3072, r = idx % 3072;
        int j = r & 7, lane = (r >> 3) & 63, rest = r >> 9;
        int ks = rest & 1, ct = rest >> 1;
        int quad = lane >> 4, m = lane & 15;
        int col = ct * 16 + m;
        int k = l * 64 + ks * 32 + quad * 8 + j;
        wpack[36864 + idx] = (col < OUT_DIM)
            ? f16bits(ldext(lin_w, f32, (size_t)k * OUT_DIM + col)) : (unsigned short)0;
    }
}

// convert x (N x 128) to bf16 if input is fp32; no-op if already bf16
__global__ __launch_bounds__(256) void convert_x_kernel(const void* x, const int* __restrict__ flags,
                                                        __hip_bfloat16* __restrict__ xbf) {
    if (flags[0] == 0) return;
    int i = blockIdx.x * 256 + threadIdx.x;  // 4 floats per thread
    const float4* src = (const float4*)x;
    float4 v = src[i];
    *(uint2*)(xbf + (size_t)i * 4) = make_uint2(pack_bf16x2(v.x, v.y), pack_bf16x2(v.z, v.w));
}

__global__ __launch_bounds__(256) void zero_int_kernel(int* p, int n) {
    int i = blockIdx.x * 256 + threadIdx.x;
    if (i < n) p[i] = 0;
}

// ---------- phase 1: LDS counting-sort append into per-bucket FIFOs ----------
__global__ __launch_bounds__(256) void bucket1_kernel(const void* ei_raw, const int* __restrict__ flags,
                                                      int* __restrict__ gcur, int* __restrict__ fifo) {
    __shared__ int lhist[NBUK];
    __shared__ int lbase[NBUK];
    bool is64 = flags[1] != 0;
    int t = threadIdx.x;
    for (int i = t; i < NBUK; i += 256) lhist[i] = 0;
    __syncthreads();
    int e0 = blockIdx.x * S1_EPB;
    int rec[8], bk[8], loff[8];
#pragma unroll
    for (int j = 0; j < 8; j++) {
        int e = e0 + j * 256 + t;
        bk[j] = -1;
        if (e < N_EDGES) {
            int s = load_edge(ei_raw, is64, e);
            int d = load_edge(ei_raw, is64, (long long)N_EDGES + e);
            int b = d >> 9;
            bk[j] = b;
            rec[j] = ((d & 511) << 17) | s;
            loff[j] = atomicAdd(&lhist[b], 1);
        }
    }
    __syncthreads();
    for (int i = t; i < NBUK; i += 256)
        lbase[i] = (lhist[i] > 0) ? atomicAdd(&gcur[i], lhist[i]) : 0;
    __syncthreads();
#pragma unroll
    for (int j = 0; j < 8; j++) {
        if (bk[j] >= 0) {
            int idx = lbase[bk[j]] + loff[j];
            if (idx < BUK_CAP) fifo[bk[j] * BUK_CAP + idx] = rec[j];
        }
    }
}

// ---------- degree from FIFO (LDS counters, zero global atomics) ----------
__global__ __launch_bounds__(256) void deg_fifo_kernel(const int* __restrict__ gcur,
                                                       const int* __restrict__ fifo,
                                                       int* __restrict__ deg) {
    __shared__ int ldeg[512];
    int b = blockIdx.x, t = threadIdx.x;
    ldeg[t] = 0;
    ldeg[t + 256] = 0;
    __syncthreads();
    int cnt = min(gcur[b], BUK_CAP);
    for (int i = t; i < cnt; i += 256)
        atomicAdd(&ldeg[fifo[b * BUK_CAP + i] >> 17], 1);
    __syncthreads();
    int n0 = b * 512 + t;
    if (n0 < N_NODES) deg[n0] = ldeg[t];
    if (n0 + 256 < N_NODES) deg[n0 + 256] = ldeg[t + 256];
}

__global__ __launch_bounds__(256) void calc_dis_kernel(const int* __restrict__ deg,
                                                       float* __restrict__ dis) {
    int i = blockIdx.x * 256 + threadIdx.x;
    if (i < N_NODES) dis[i] = rsqrtf((float)(deg[i] + 1));  // +1 self-loop
}

// exclusive scan of deg -> row (3-kernel, 1024 elems/block)
__global__ __launch_bounds__(256) void scan1_kernel(const int* __restrict__ deg, int* __restrict__ row,
                                                    int* __restrict__ bsums) {
    __shared__ int sd[256];
    int t = threadIdx.x;
    int base = blockIdx.x * 1024 + t * 4;
    int v[4];
#pragma unroll
    for (int j = 0; j < 4; j++) {
        int idx = base + j;
        v[j] = (idx < N_NODES) ? deg[idx] : 0;
    }
    int s4 = v[0] + v[1] + v[2] + v[3];
    sd[t] = s4;
    __syncthreads();
    for (int off = 1; off < 256; off <<= 1) {
        int x = (t >= off) ? sd[t - off] : 0;
        __syncthreads();
        sd[t] += x;
        __syncthreads();
    }
    int run = sd[t] - s4;  // exclusive
#pragma unroll
    for (int j = 0; j < 4; j++) {
        int idx = base + j;
        if (idx < N_NODES) row[idx] = run;
        run += v[j];
    }
    if (t == 255) bsums[blockIdx.x] = sd[255];
}

__global__ void scan2_kernel(int* bsums) {
    __shared__ int sd[128];
    int t = threadIdx.x;
    int v = (t < SCAN_NB) ? bsums[t] : 0;
    sd[t] = v;
    __syncthreads();
    for (int off = 1; off < 128; off <<= 1) {
        int x = (t >= off) ? sd[t - off] : 0;
        __syncthreads();
        sd[t] += x;
        __syncthreads();
    }
    if (t < SCAN_NB) bsums[t] = sd[t] - v;  // exclusive block offsets
}

__global__ __launch_bounds__(256) void scan3_kernel(int* __restrict__ row, const int* __restrict__ bsums) {
    int i = blockIdx.x * 256 + threadIdx.x;
    if (i < N_NODES) row[i] += bsums[i >> 10];
    if (i == 0) row[N_NODES] = N_EDGES;
}

// ---------- phase 2: per-bucket scatter to final CSR with LDS cursors ----------
__global__ __launch_bounds__(256) void bucket2_kernel(const int* __restrict__ gcur,
                                                      const int* __restrict__ fifo,
                                                      const int* __restrict__ row,
                                                      int* __restrict__ csr_src) {
    __shared__ int lcur[512];
    int b = blockIdx.x, t = threadIdx.x;
    int n0 = b * 512 + t;
    lcur[t] = row[min(n0, N_NODES)];
    lcur[t + 256] = row[min(n0 + 256, N_NODES)];
    __syncthreads();
    int cnt = min(gcur[b], BUK_CAP);
    for (int i = t; i < cnt; i += 256) {
        int r = fifo[b * BUK_CAP + i];
        int pos = atomicAdd(&lcur[r >> 17], 1);
        csr_src[pos] = r & 0x1FFFF;
    }
}

// ---------- MFMA matmul: t0s (f16, 4 quarter-slices, dis-prescaled) = dis .* (h @ W) ----------
// ABF16: A/wW are bf16 (layer 0, A = x); else f16 (A = h).
// JK: 0 = none, 1 = out_acc = h @ lwB, 2 = out_acc += h @ lwB (exclusive per node)
template <int KS, int JK, bool ABF16>
__global__ __launch_bounds__(256) void mm_mfma_kernel(const void* __restrict__ h0,
                                                      const void* __restrict__ h1,
                                                      const int* __restrict__ flags,
                                                      const unsigned short* __restrict__ wW,
                                                      const unsigned short* __restrict__ wJ,
                                                      const float* __restrict__ dis,
                                                      __half* __restrict__ t0s,
                                                      float* __restrict__ out_acc) {
    constexpr int K = KS * 32;
    const short* hsrc = (const short*)(flags[0] ? h1 : h0);
    int wave = threadIdx.x >> 6, lane = threadIdx.x & 63;
    int quad = lane >> 4, m = lane & 15;
    int nb = blockIdx.x * 64 + wave * 16;
    int ra = nb + m;
    if (ra > N_NODES - 1) ra = N_NODES - 1;  // clamp tail (avoids OOB read)
    const short* hrow = hsrc + (size_t)ra * K + quad * 8;
    short8 a[KS];
#pragma unroll
    for (int ks = 0; ks < KS; ks++) a[ks] = *(const short8*)(hrow + ks * 32);
    float dr[4];
#pragma unroll
    for (int r = 0; r < 4; r++) {
        int rw = nb + quad * 4 + r;
        dr[r] = dis[rw < N_NODES ? rw : (N_NODES - 1)];
    }
#pragma unroll
    for (int ct = 0; ct < 4; ct++) {
        float4v acc = (float4v){0.f, 0.f, 0.f, 0.f};
#pragma unroll
        for (int ks = 0; ks < KS; ks++) {
            short8 b = *(const short8*)(wW + ((ct * KS + ks) * 64 + lane) * 8);
            if constexpr (ABF16)
                acc = __builtin_amdgcn_mfma_f32_16x16x32_bf16(a[ks], b, acc, 0, 0, 0);
            else
                acc = __builtin_amdgcn_mfma_f32_16x16x32_f16(
                    __builtin_bit_cast(half8, a[ks]), __builtin_bit_cast(half8, b), acc, 0, 0, 0);
        }
        // quarter-slice ct holds features ct*16..ct*16+15
#pragma unroll
        for (int r = 0; r < 4; r++) {
            t0s[(size_t)ct * T0SL4 + (size_t)(nb + quad * 4 + r) * 16 + m] =
                __float2half(acc[r] * dr[r]);
        }
    }
    if (JK) {
#pragma unroll
        for (int ct = 0; ct < 3; ct++) {
            float4v j = (float4v){0.f, 0.f, 0.f, 0.f};
#pragma unroll
            for (int ks = 0; ks < KS; ks++) {
                short8 b = *(const short8*)(wJ + ((ct * KS + ks) * 64 + lane) * 8);
                if constexpr (ABF16)
                    j = __builtin_amdgcn_mfma_f32_16x16x32_bf16(a[ks], b, j, 0, 0, 0);
                else
                    j = __builtin_amdgcn_mfma_f32_16x16x32_f16(
                        __builtin_bit_cast(half8, a[ks]), __builtin_bit_cast(half8, b), j, 0, 0, 0);
            }
            int col = ct * 16 + m;
            if (col < OUT_DIM) {
#pragma unroll
                for (int r = 0; r < 4; r++) {
                    int rw = nb + quad * 4 + r;
                    if (rw < N_NODES) {
                        size_t o = (size_t)rw * OUT_DIM + col;
                        if (JK == 1) out_acc[o] = j[r];
                        else out_acc[o] += j[r];
                    }
                }
            }
        }
    }
}

// ---------- aggregation: 4 XCD-affine quarter-slices + block-staged csr ----------
// block b: slice s = b&3 (3.2MB slice resident in the serving XCDs' L2),
// nodes nb..nb+63. csr range staged to LDS once (NT, coalesced, amortized).
// wave = node; lane = ep*2+fp: 32 edges in flight x 16B (8 f16 feats) per lane.
__global__ __launch_bounds__(256) void agg_kernel(const __half* __restrict__ t0s,
                                                  const int* __restrict__ row,
                                                  const int* __restrict__ csr_src,
                                                  const float* __restrict__ dis,
                                                  const float* __restrict__ bsf,   // this layer, 64 f32
                                                  __half* __restrict__ h) {
    __shared__ int lrow[AGG_N + 1];
    __shared__ int lcsr[AGG_CAP];
    int t = threadIdx.x;
    int s = blockIdx.x & 3;
    int nb = (blockIdx.x >> 2) * AGG_N;
    const __half* tsl = t0s + (size_t)s * T0SL4;

    for (int i = t; i <= AGG_N; i += 256) {
        int n = nb + i;
        lrow[i] = row[n > N_NODES ? N_NODES : n];
    }
    __syncthreads();
    int rs0 = lrow[0];
    int cnt = lrow[AGG_N] - rs0;
    for (int i = t; i < cnt && i < AGG_CAP; i += 256)
        lcsr[i] = __builtin_nontemporal_load(&csr_src[rs0 + i]);
    __syncthreads();

    int wave = t >> 6, lane = t & 63;
    int ep = lane >> 1, fp = lane & 1;
    for (int nl = wave; nl < AGG_N; nl += 4) {
        int node = nb + nl;
        if (node >= N_NODES) break;
        int rs = lrow[nl], re = lrow[nl + 1];
        __half2 a2[4];
#pragma unroll
        for (int r = 0; r < 4; r++) a2[r] = __floats2half2_rn(0.f, 0.f);
        if (ep == 0) {  // self-loop (prescaled row)
            uint4 v = *(const uint4*)(tsl + (size_t)node * 16 + fp * 8);
            a2[0] = __hadd2(a2[0], u2h2(v.x));
            a2[1] = __hadd2(a2[1], u2h2(v.y));
            a2[2] = __hadd2(a2[2], u2h2(v.z));
            a2[3] = __hadd2(a2[3], u2h2(v.w));
        }
        for (int base = rs; base + ep < re; base += 32) {
            int idx = base + ep - rs0;
            int se = (idx < AGG_CAP) ? lcsr[idx] : csr_src[base + ep];
            uint4 v = *(const uint4*)(tsl + (size_t)se * 16 + fp * 8);  // L2-resident gather
            a2[0] = __hadd2(a2[0], u2h2(v.x));
            a2[1] = __hadd2(a2[1], u2h2(v.y));
            a2[2] = __hadd2(a2[2], u2h2(v.z));
            a2[3] = __hadd2(a2[3], u2h2(v.w));
        }
        // reduce over ep (lane bits 1..5)
#pragma unroll
        for (int st = 2; st <= 32; st <<= 1) {
#pragma unroll
            for (int r = 0; r < 4; r++)
                a2[r] = __hadd2(a2[r], u2h2(__shfl_xor(h22u(a2[r]), st)));
        }
        float di = dis[node];
        const float* bb = bsf + s * 16 + fp * 8;
        float a[8];
#pragma unroll
        for (int r = 0; r < 4; r++) {
            a[2 * r]     = __low2float(a2[r]);
            a[2 * r + 1] = __high2float(a2[r]);
        }
#pragma unroll
        for (int j = 0; j < 8; j++) a[j] = fmaxf(di * a[j] + bb[j], 0.f);
        if (ep == 0) {
            uint4 pv;
            pv.x = h22u(__floats2half2_rn(a[0], a[1]));
            pv.y = h22u(__floats2half2_rn(a[2], a[3]));
            pv.z = h22u(__floats2half2_rn(a[4], a[5]));
            pv.w = h22u(__floats2half2_rn(a[6], a[7]));
            *(uint4*)(h + (size_t)node * 64 + s * 16 + fp * 8) = pv;
        }
    }
}

// ---------- final: out = out_acc + h7 @ lwB7 + lin_b ----------
__global__ __launch_bounds__(256) void jk_final_kernel(const __half* __restrict__ h,
                                                       const unsigned short* __restrict__ wJ,
                                                       const float* __restrict__ out_acc,
                                                       const void* __restrict__ lin_b,
                                                       const int* __restrict__ flags,
                                                       void* __restrict__ d_out) {
    bool f32 = flags[0] != 0;
    int wave = threadIdx.x >> 6, lane = threadIdx.x & 63;
    int quad = lane >> 4, m = lane & 15;
    int nb = blockIdx.x * 64 + wave * 16;
    int ra = nb + m;
    if (ra > N_NODES - 1) ra = N_NODES - 1;
    const short* hrow = (const short*)(h + (size_t)ra * 64) + quad * 8;
    short8 a0 = *(const short8*)(hrow);
    short8 a1 = *(const short8*)(hrow + 32);
#pragma unroll
    for (int ct = 0; ct < 3; ct++) {
        float4v j = (float4v){0.f, 0.f, 0.f, 0.f};
        short8 b0 = *(const short8*)(wJ + ((ct * 2 + 0) * 64 + lane) * 8);
        short8 b1 = *(const short8*)(wJ + ((ct * 2 + 1) * 64 + lane) * 8);
        j = __builtin_amdgcn_mfma_f32_16x16x32_f16(
            __builtin_bit_cast(half8, a0), __builtin_bit_cast(half8, b0), j, 0, 0, 0);
        j = __builtin_amdgcn_mfma_f32_16x16x32_f16(
            __builtin_bit_cast(half8, a1), __builtin_bit_cast(half8, b1), j, 0, 0, 0);
        int col = ct * 16 + m;
        if (col < OUT_DIM) {
            float lb = ldext(lin_b, f32, col);
#pragma unroll
            for (int r = 0; r < 4; r++) {
                int rw = nb + quad * 4 + r;
                if (rw < N_NODES) {
                    float v = out_acc[(size_t)rw * OUT_DIM + col] + j[r] + lb;
                    if (f32) ((float*)d_out)[(size_t)rw * OUT_DIM + col] = v;
                    else ((__hip_bfloat16*)d_out)[(size_t)rw * OUT_DIM + col] = __float2bfloat16(v);
                }
            }
        }
    }
}

extern "C" void kernel_launch(void* const* d_in, const int* in_sizes, int n_in,
                              void* d_out, int out_size, void* d_ws, size_t ws_size,
                              hipStream_t stream) {
    const void* x     = d_in[0];
    const void* W0    = d_in[1];
    const void* Ws    = d_in[2];
    const void* bs    = d_in[3];
    const void* lin_w = d_in[4];
    const void* lin_b = d_in[5];
    const void* ei    = d_in[6];

    size_t off = 0;
    auto alloc = [&](size_t bytes) -> void* {
        void* p = (char*)d_ws + off;
        off += (bytes + 511) & ~(size_t)511;
        return p;
    };
    int*   flags   = (int*)alloc(512);
    float* dis     = (float*)alloc((size_t)(N_NODES + 64) * 4);
    int*   deg     = (int*)alloc((size_t)N_NODES * 4);
    int*   row     = (int*)alloc((size_t)(N_NODES + 1) * 4);
    int*   bsums   = (int*)alloc(128 * 4);
    int*   gcur    = (int*)alloc((size_t)NBUK * 4);
    int*   fifo    = (int*)alloc((size_t)NBUK * BUK_CAP * 4);   // 9.4 MB
    int*   csr_src = (int*)alloc((size_t)N_EDGES * 4);
    __half* t0s = (__half*)alloc((size_t)4 * T0SL4 * 2);
    __half* h   = (__half*)alloc((size_t)(N_NODES + 32) * HID * 2);
    __hip_bfloat16* xbf = (__hip_bfloat16*)alloc((size_t)(N_NODES + 32) * 128 * 2);
    float* out_acc = (float*)alloc((size_t)N_NODES * OUT_DIM * 4);
    float* bsf     = (float*)alloc((size_t)LAYERS * HID * 4);
    unsigned short* wpack = (unsigned short*)alloc((size_t)61440 * 2);

    const int nblkN  = (N_NODES + 255) / 256;
    const int nblkS1 = (N_EDGES + S1_EPB - 1) / S1_EPB;  // 782
    const int nblkMM = (N_NODES + 63) / 64;              // 1563
    const int nblkAG = nblkMM * 4;                       // 6252

    detect_kernel<<<1, 64, 0, stream>>>(x, ei, flags);
    pack_params_kernel<<<80, 256, 0, stream>>>(bs, lin_w, W0, Ws, flags, bsf, wpack);
    convert_x_kernel<<<(N_NODES * 128 / 4) / 256, 256, 0, stream>>>(x, flags, xbf);
    zero_int_kernel<<<1, 256, 0, stream>>>(gcur, NBUK);
    bucket1_kernel<<<nblkS1, 256, 0, stream>>>(ei, flags, gcur, fifo);
    deg_fifo_kernel<<<NBUK, 256, 0, stream>>>(gcur, fifo, deg);
    calc_dis_kernel<<<nblkN, 256, 0, stream>>>(deg, dis);
    scan1_kernel<<<SCAN_NB, 256, 0, stream>>>(deg, row, bsums);
    scan2_kernel<<<1, 128, 0, stream>>>(bsums);
    scan3_kernel<<<nblkN, 256, 0, stream>>>(row, bsums);
    bucket2_kernel<<<NBUK, 256, 0, stream>>>(gcur, fifo, row, csr_src);

    const unsigned short* wJ0 = wpack + 36864;
    for (int l = 0; l < LAYERS; l++) {
        if (l == 0) {
            mm_mfma_kernel<4, 0, true><<<nblkMM, 256, 0, stream>>>(
                x, xbf, flags, wpack, nullptr, dis, t0s, nullptr);
        } else if (l == 1) {
            mm_mfma_kernel<2, 1, false><<<nblkMM, 256, 0, stream>>>(
                h, h, flags, wpack + 8192, wJ0, dis, t0s, out_acc);
        } else {
            mm_mfma_kernel<2, 2, false><<<nblkMM, 256, 0, stream>>>(
                h, h, flags, wpack + 8192 + (size_t)(l - 1) * 4096,
                wJ0 + (size_t)(l - 1) * 3072, dis, t0s, out_acc);
        }
        agg_kernel<<<nblkAG, 256, 0, stream>>>(t0s, row, csr_src, dis,
                                               bsf + (size_t)l * HID, h);
    }
    jk_final_kernel<<<nblkMM, 256, 0, stream>>>(h, wJ0 + (size_t)7 * 3072, out_acc,
                                                lin_b, flags, d_out);
}

// Round 10
// 721.492 us; speedup vs baseline: 1.6097x; 1.6097x over previous
//
#include <hip/hip_runtime.h>
#include <hip/hip_bf16.h>
#include <hip/hip_fp16.h>

#define N_NODES 100000
#define N_EDGES 1600000
#define HID     64
#define LAYERS  8
#define OUT_DIM 40
#define SCAN_NB 98   // ceil(100000/1024)
#define T0SL4   ((size_t)(N_NODES + 32) * 16)   // elements per t0 quarter-slice (16 feats)
#define NBUK    196      // ceil(100000/512) buckets of 512 nodes
#define BUK_CAP 12000    // avg 8163/bucket -> huge sigma headroom
#define S1_EPB  2048     // edges per bucket1 block (256 thr x 8)
#define AGG_N   128      // nodes per agg block
#define AGG_CAP 3072     // staged csr entries (mean 2048, +22 sigma), 12KB LDS

typedef __attribute__((ext_vector_type(8))) short short8;
typedef __attribute__((ext_vector_type(8))) _Float16 half8;
typedef __attribute__((ext_vector_type(4))) float float4v;

// ---------- runtime environment hedges ----------
// flags[0] = 1 if feature inputs are float32 (else bf16)
// flags[1] = 1 if edge_index is int64 (else int32)
__device__ inline float ldext(const void* p, bool f32, size_t i) {
    return f32 ? ((const float*)p)[i]
               : __bfloat162float(((const __hip_bfloat16*)p)[i]);
}
__device__ inline int load_edge(const void* raw, bool is64, long long idx) {
    return is64 ? (int)((const long long*)raw)[idx] : ((const int*)raw)[idx];
}
__device__ inline unsigned pack_bf16x2(float lo, float hi) {
    union { __hip_bfloat16 b; unsigned short u; } a, b;
    a.b = __float2bfloat16(lo);
    b.b = __float2bfloat16(hi);
    return ((unsigned)b.u << 16) | a.u;
}
__device__ inline unsigned short bf16bits(float v) {
    union { __hip_bfloat16 b; unsigned short u; } a;
    a.b = __float2bfloat16(v);
    return a.u;
}
__device__ inline unsigned short f16bits(float v) {
    union { __half h; unsigned short u; } a;
    a.h = __float2half_rn(v);
    return a.u;
}
__device__ inline __half2 u2h2(unsigned u) {
    union { unsigned u; __half2 h; } x; x.u = u; return x.h;
}
__device__ inline unsigned h22u(__half2 h) {
    union { unsigned u; __half2 h; } x; x.h = h; return x.u;
}

__global__ void detect_kernel(const void* x, const void* ei, int* flags) {
    int t = threadIdx.x;  // 64 threads
    float v = fabsf(__bfloat162float(((const __hip_bfloat16*)x)[t]));
    bool inband = (v >= 0.00390625f && v <= 16.0f);
    unsigned long long m = __ballot(inband);
    if (t == 0) {
        flags[0] = (__popcll(m) < 48) ? 1 : 0;  // fp32 misread as bf16 -> ~33/64 in band
        const int* e32 = (const int*)ei;
        flags[1] = ((e32[1] | e32[3] | e32[5] | e32[7]) == 0) ? 1 : 0;
    }
}

// pack: bias (fp32); W0 as bf16 MFMA B-frags; W1..7 and lwB as f16 MFMA B-frags.
__global__ __launch_bounds__(256) void pack_params_kernel(const void* bs, const void* lin_w,
                                                          const void* W0, const void* Ws,
                                                          const int* __restrict__ flags,
                                                          float* __restrict__ bsf,
                                                          unsigned short* __restrict__ wpack) {
    bool f32 = flags[0] != 0;
    int gid = blockIdx.x * 256 + threadIdx.x;
    int stride = gridDim.x * 256;
    for (int idx = gid; idx < LAYERS * HID; idx += stride) bsf[idx] = ldext(bs, f32, idx);
    // layer 0 W: K=128 (KS=4), 8192 elements, bf16 (A = x is bf16)
    for (int idx = gid; idx < 8192; idx += stride) {
        int j = idx & 7, lane = (idx >> 3) & 63, rest = idx >> 9;
        int ks = rest & 3, ct = rest >> 2;
        int quad = lane >> 4, m = lane & 15;
        wpack[idx] = bf16bits(ldext(W0, f32, (size_t)(ks * 32 + quad * 8 + j) * 64 + ct * 16 + m));
    }
    // layers 1..7 W: K=64 (KS=2), 4096 each, f16 (A = h is f16)
    for (int idx = gid; idx < 7 * 4096; idx += stride) {
        int l = idx >> 12, r = idx & 4095;
        int j = r & 7, lane = (r >> 3) & 63, rest = r >> 9;
        int ks = rest & 1, ct = rest >> 1;
        int quad = lane >> 4, m = lane & 15;
        wpack[8192 + idx] = f16bits(
            ldext(Ws, f32, (size_t)l * 4096 + (size_t)(ks * 32 + quad * 8 + j) * 64 + ct * 16 + m));
    }
    // lwB: 8 layers x 3072 (3 ct x 2 ks x 64 lanes x 8), f16
    for (int idx = gid; idx < LAYERS * 3072; idx += stride) {
        int l = idx / 3072, r = idx % 3072;
        int j = r & 7, lane = (r >> 3) & 63, rest = r >> 9;
        int ks = rest & 1, ct = rest >> 1;
        int quad = lane >> 4, m = lane & 15;
        int col = ct * 16 + m;
        int k = l * 64 + ks * 32 + quad * 8 + j;
        wpack[36864 + idx] = (col < OUT_DIM)
            ? f16bits(ldext(lin_w, f32, (size_t)k * OUT_DIM + col)) : (unsigned short)0;
    }
}

// convert x (N x 128) to bf16 if input is fp32; no-op if already bf16
__global__ __launch_bounds__(256) void convert_x_kernel(const void* x, const int* __restrict__ flags,
                                                        __hip_bfloat16* __restrict__ xbf) {
    if (flags[0] == 0) return;
    int i = blockIdx.x * 256 + threadIdx.x;  // 4 floats per thread
    const float4* src = (const float4*)x;
    float4 v = src[i];
    *(uint2*)(xbf + (size_t)i * 4) = make_uint2(pack_bf16x2(v.x, v.y), pack_bf16x2(v.z, v.w));
}

__global__ __launch_bounds__(256) void zero_int_kernel(int* p, int n) {
    int i = blockIdx.x * 256 + threadIdx.x;
    if (i < n) p[i] = 0;
}

// ---------- phase 1: LDS counting-sort append into per-bucket FIFOs ----------
__global__ __launch_bounds__(256) void bucket1_kernel(const void* ei_raw, const int* __restrict__ flags,
                                                      int* __restrict__ gcur, int* __restrict__ fifo) {
    __shared__ int lhist[NBUK];
    __shared__ int lbase[NBUK];
    bool is64 = flags[1] != 0;
    int t = threadIdx.x;
    for (int i = t; i < NBUK; i += 256) lhist[i] = 0;
    __syncthreads();
    int e0 = blockIdx.x * S1_EPB;
    int rec[8], bk[8], loff[8];
#pragma unroll
    for (int j = 0; j < 8; j++) {
        int e = e0 + j * 256 + t;
        bk[j] = -1;
        if (e < N_EDGES) {
            int s = load_edge(ei_raw, is64, e);
            int d = load_edge(ei_raw, is64, (long long)N_EDGES + e);
            int b = d >> 9;
            bk[j] = b;
            rec[j] = ((d & 511) << 17) | s;
            loff[j] = atomicAdd(&lhist[b], 1);
        }
    }
    __syncthreads();
    for (int i = t; i < NBUK; i += 256)
        lbase[i] = (lhist[i] > 0) ? atomicAdd(&gcur[i], lhist[i]) : 0;
    __syncthreads();
#pragma unroll
    for (int j = 0; j < 8; j++) {
        if (bk[j] >= 0) {
            int idx = lbase[bk[j]] + loff[j];
            if (idx < BUK_CAP) fifo[bk[j] * BUK_CAP + idx] = rec[j];
        }
    }
}

// ---------- degree from FIFO (LDS counters, zero global atomics) ----------
__global__ __launch_bounds__(256) void deg_fifo_kernel(const int* __restrict__ gcur,
                                                       const int* __restrict__ fifo,
                                                       int* __restrict__ deg) {
    __shared__ int ldeg[512];
    int b = blockIdx.x, t = threadIdx.x;
    ldeg[t] = 0;
    ldeg[t + 256] = 0;
    __syncthreads();
    int cnt = min(gcur[b], BUK_CAP);
    for (int i = t; i < cnt; i += 256)
        atomicAdd(&ldeg[fifo[b * BUK_CAP + i] >> 17], 1);
    __syncthreads();
    int n0 = b * 512 + t;
    if (n0 < N_NODES) deg[n0] = ldeg[t];
    if (n0 + 256 < N_NODES) deg[n0 + 256] = ldeg[t + 256];
}

__global__ __launch_bounds__(256) void calc_dis_kernel(const int* __restrict__ deg,
                                                       float* __restrict__ dis) {
    int i = blockIdx.x * 256 + threadIdx.x;
    if (i < N_NODES) dis[i] = rsqrtf((float)(deg[i] + 1));  // +1 self-loop
}

// exclusive scan of deg -> row (3-kernel, 1024 elems/block)
__global__ __launch_bounds__(256) void scan1_kernel(const int* __restrict__ deg, int* __restrict__ row,
                                                    int* __restrict__ bsums) {
    __shared__ int sd[256];
    int t = threadIdx.x;
    int base = blockIdx.x * 1024 + t * 4;
    int v[4];
#pragma unroll
    for (int j = 0; j < 4; j++) {
        int idx = base + j;
        v[j] = (idx < N_NODES) ? deg[idx] : 0;
    }
    int s4 = v[0] + v[1] + v[2] + v[3];
    sd[t] = s4;
    __syncthreads();
    for (int off = 1; off < 256; off <<= 1) {
        int x = (t >= off) ? sd[t - off] : 0;
        __syncthreads();
        sd[t] += x;
        __syncthreads();
    }
    int run = sd[t] - s4;  // exclusive
#pragma unroll
    for (int j = 0; j < 4; j++) {
        int idx = base + j;
        if (idx < N_NODES) row[idx] = run;
        run += v[j];
    }
    if (t == 255) bsums[blockIdx.x] = sd[255];
}

__global__ void scan2_kernel(int* bsums) {
    __shared__ int sd[128];
    int t = threadIdx.x;
    int v = (t < SCAN_NB) ? bsums[t] : 0;
    sd[t] = v;
    __syncthreads();
    for (int off = 1; off < 128; off <<= 1) {
        int x = (t >= off) ? sd[t - off] : 0;
        __syncthreads();
        sd[t] += x;
        __syncthreads();
    }
    if (t < SCAN_NB) bsums[t] = sd[t] - v;  // exclusive block offsets
}

__global__ __launch_bounds__(256) void scan3_kernel(int* __restrict__ row, const int* __restrict__ bsums) {
    int i = blockIdx.x * 256 + threadIdx.x;
    if (i < N_NODES) row[i] += bsums[i >> 10];
    if (i == 0) row[N_NODES] = N_EDGES;
}

// ---------- phase 2: per-bucket scatter to final CSR with LDS cursors ----------
__global__ __launch_bounds__(256) void bucket2_kernel(const int* __restrict__ gcur,
                                                      const int* __restrict__ fifo,
                                                      const int* __restrict__ row,
                                                      int* __restrict__ csr_src) {
    __shared__ int lcur[512];
    int b = blockIdx.x, t = threadIdx.x;
    int n0 = b * 512 + t;
    lcur[t] = row[min(n0, N_NODES)];
    lcur[t + 256] = row[min(n0 + 256, N_NODES)];
    __syncthreads();
    int cnt = min(gcur[b], BUK_CAP);
    for (int i = t; i < cnt; i += 256) {
        int r = fifo[b * BUK_CAP + i];
        int pos = atomicAdd(&lcur[r >> 17], 1);
        csr_src[pos] = r & 0x1FFFF;
    }
}

// ---------- MFMA matmul: t0s (f16, 4 quarter-slices, dis-prescaled) = dis .* (h @ W) ----------
// ABF16: A/wW are bf16 (layer 0, A = x); else f16 (A = h).
// JK: 0 = none, 1 = out_acc = h @ lwB, 2 = out_acc += h @ lwB (exclusive per node)
template <int KS, int JK, bool ABF16>
__global__ __launch_bounds__(256) void mm_mfma_kernel(const void* __restrict__ h0,
                                                      const void* __restrict__ h1,
                                                      const int* __restrict__ flags,
                                                      const unsigned short* __restrict__ wW,
                                                      const unsigned short* __restrict__ wJ,
                                                      const float* __restrict__ dis,
                                                      __half* __restrict__ t0s,
                                                      float* __restrict__ out_acc) {
    constexpr int K = KS * 32;
    const short* hsrc = (const short*)(flags[0] ? h1 : h0);
    int wave = threadIdx.x >> 6, lane = threadIdx.x & 63;
    int quad = lane >> 4, m = lane & 15;
    int nb = blockIdx.x * 64 + wave * 16;
    int ra = nb + m;
    if (ra > N_NODES - 1) ra = N_NODES - 1;  // clamp tail (avoids OOB read)
    const short* hrow = hsrc + (size_t)ra * K + quad * 8;
    short8 a[KS];
#pragma unroll
    for (int ks = 0; ks < KS; ks++) a[ks] = *(const short8*)(hrow + ks * 32);
    float dr[4];
#pragma unroll
    for (int r = 0; r < 4; r++) {
        int rw = nb + quad * 4 + r;
        dr[r] = dis[rw < N_NODES ? rw : (N_NODES - 1)];
    }
#pragma unroll
    for (int ct = 0; ct < 4; ct++) {
        float4v acc = (float4v){0.f, 0.f, 0.f, 0.f};
#pragma unroll
        for (int ks = 0; ks < KS; ks++) {
            short8 b = *(const short8*)(wW + ((ct * KS + ks) * 64 + lane) * 8);
            if constexpr (ABF16)
                acc = __builtin_amdgcn_mfma_f32_16x16x32_bf16(a[ks], b, acc, 0, 0, 0);
            else
                acc = __builtin_amdgcn_mfma_f32_16x16x32_f16(
                    __builtin_bit_cast(half8, a[ks]), __builtin_bit_cast(half8, b), acc, 0, 0, 0);
        }
        // quarter-slice ct holds features ct*16..ct*16+15
#pragma unroll
        for (int r = 0; r < 4; r++) {
            t0s[(size_t)ct * T0SL4 + (size_t)(nb + quad * 4 + r) * 16 + m] =
                __float2half(acc[r] * dr[r]);
        }
    }
    if (JK) {
#pragma unroll
        for (int ct = 0; ct < 3; ct++) {
            float4v j = (float4v){0.f, 0.f, 0.f, 0.f};
#pragma unroll
            for (int ks = 0; ks < KS; ks++) {
                short8 b = *(const short8*)(wJ + ((ct * KS + ks) * 64 + lane) * 8);
                if constexpr (ABF16)
                    j = __builtin_amdgcn_mfma_f32_16x16x32_bf16(a[ks], b, j, 0, 0, 0);
                else
                    j = __builtin_amdgcn_mfma_f32_16x16x32_f16(
                        __builtin_bit_cast(half8, a[ks]), __builtin_bit_cast(half8, b), j, 0, 0, 0);
            }
            int col = ct * 16 + m;
            if (col < OUT_DIM) {
#pragma unroll
                for (int r = 0; r < 4; r++) {
                    int rw = nb + quad * 4 + r;
                    if (rw < N_NODES) {
                        size_t o = (size_t)rw * OUT_DIM + col;
                        if (JK == 1) out_acc[o] = j[r];
                        else out_acc[o] += j[r];
                    }
                }
            }
        }
    }
}

// ---------- aggregation: 4 XCD-affine quarter-slices, staged csr, 4 nodes/wave ----------
// block b: slice s = b&3 (3.2MB slice L2-resident), nodes nb..nb+127.
// csr staged once to LDS (NT, coalesced). wave pass = 4 nodes in parallel:
// lane = ns(4)*16 + ep(8)*2 + fp(2); 8 edges in flight per node, 16B/lane gathers,
// 3-stage shuffle reduce (xor 2,4,8). 8 passes cover the block.
__global__ __launch_bounds__(256) void agg_kernel(const __half* __restrict__ t0s,
                                                  const int* __restrict__ row,
                                                  const int* __restrict__ csr_src,
                                                  const float* __restrict__ dis,
                                                  const float* __restrict__ bsf,   // this layer, 64 f32
                                                  __half* __restrict__ h) {
    __shared__ int lrow[AGG_N + 1];
    __shared__ int lcsr[AGG_CAP];
    int t = threadIdx.x;
    int s = blockIdx.x & 3;
    int nb = (blockIdx.x >> 2) * AGG_N;
    const __half* tsl = t0s + (size_t)s * T0SL4;

    for (int i = t; i <= AGG_N; i += 256) {
        int n = nb + i;
        lrow[i] = row[n > N_NODES ? N_NODES : n];
    }
    __syncthreads();
    int rs0 = lrow[0];
    int cnt = min(lrow[AGG_N] - rs0, AGG_CAP);
    for (int i = t; i < cnt; i += 256)
        lcsr[i] = __builtin_nontemporal_load(&csr_src[rs0 + i]);
    __syncthreads();

    int wave = t >> 6, lane = t & 63;
    int ns = lane >> 4, ep = (lane >> 1) & 7, fp = lane & 1;
#pragma unroll
    for (int pass = 0; pass < AGG_N / 16; pass++) {
        int nl = pass * 16 + wave * 4 + ns;
        int node = nb + nl;
        bool valid = node < N_NODES;
        int rs = valid ? lrow[nl] : 0;
        int re = valid ? lrow[nl + 1] : 0;
        __half2 a2[4];
#pragma unroll
        for (int r = 0; r < 4; r++) a2[r] = __floats2half2_rn(0.f, 0.f);
        if (valid && ep == 0) {  // self-loop (prescaled row)
            uint4 v = *(const uint4*)(tsl + (size_t)node * 16 + fp * 8);
            a2[0] = __hadd2(a2[0], u2h2(v.x));
            a2[1] = __hadd2(a2[1], u2h2(v.y));
            a2[2] = __hadd2(a2[2], u2h2(v.z));
            a2[3] = __hadd2(a2[3], u2h2(v.w));
        }
        for (int base = rs; base + ep < re; base += 8) {
            int idx = base + ep - rs0;
            int se = (idx < AGG_CAP) ? lcsr[idx] : csr_src[base + ep];
            uint4 v = *(const uint4*)(tsl + (size_t)se * 16 + fp * 8);  // L2-resident gather
            a2[0] = __hadd2(a2[0], u2h2(v.x));
            a2[1] = __hadd2(a2[1], u2h2(v.y));
            a2[2] = __hadd2(a2[2], u2h2(v.z));
            a2[3] = __hadd2(a2[3], u2h2(v.w));
        }
        // reduce over ep (lane bits 1..3)
#pragma unroll
        for (int st = 2; st <= 8; st <<= 1) {
#pragma unroll
            for (int r = 0; r < 4; r++)
                a2[r] = __hadd2(a2[r], u2h2(__shfl_xor(h22u(a2[r]), st)));
        }
        if (valid && ep == 0) {
            float di = dis[node];
            const float* bb = bsf + s * 16 + fp * 8;
            float a[8];
#pragma unroll
            for (int r = 0; r < 4; r++) {
                a[2 * r]     = __low2float(a2[r]);
                a[2 * r + 1] = __high2float(a2[r]);
            }
#pragma unroll
            for (int j = 0; j < 8; j++) a[j] = fmaxf(di * a[j] + bb[j], 0.f);
            uint4 pv;
            pv.x = h22u(__floats2half2_rn(a[0], a[1]));
            pv.y = h22u(__floats2half2_rn(a[2], a[3]));
            pv.z = h22u(__floats2half2_rn(a[4], a[5]));
            pv.w = h22u(__floats2half2_rn(a[6], a[7]));
            *(uint4*)(h + (size_t)node * 64 + s * 16 + fp * 8) = pv;
        }
    }
}

// ---------- final: out = out_acc + h7 @ lwB7 + lin_b ----------
__global__ __launch_bounds__(256) void jk_final_kernel(const __half* __restrict__ h,
                                                       const unsigned short* __restrict__ wJ,
                                                       const float* __restrict__ out_acc,
                                                       const void* __restrict__ lin_b,
                                                       const int* __restrict__ flags,
                                                       void* __restrict__ d_out) {
    bool f32 = flags[0] != 0;
    int wave = threadIdx.x >> 6, lane = threadIdx.x & 63;
    int quad = lane >> 4, m = lane & 15;
    int nb = blockIdx.x * 64 + wave * 16;
    int ra = nb + m;
    if (ra > N_NODES - 1) ra = N_NODES - 1;
    const short* hrow = (const short*)(h + (size_t)ra * 64) + quad * 8;
    short8 a0 = *(const short8*)(hrow);
    short8 a1 = *(const short8*)(hrow + 32);
#pragma unroll
    for (int ct = 0; ct < 3; ct++) {
        float4v j = (float4v){0.f, 0.f, 0.f, 0.f};
        short8 b0 = *(const short8*)(wJ + ((ct * 2 + 0) * 64 + lane) * 8);
        short8 b1 = *(const short8*)(wJ + ((ct * 2 + 1) * 64 + lane) * 8);
        j = __builtin_amdgcn_mfma_f32_16x16x32_f16(
            __builtin_bit_cast(half8, a0), __builtin_bit_cast(half8, b0), j, 0, 0, 0);
        j = __builtin_amdgcn_mfma_f32_16x16x32_f16(
            __builtin_bit_cast(half8, a1), __builtin_bit_cast(half8, b1), j, 0, 0, 0);
        int col = ct * 16 + m;
        if (col < OUT_DIM) {
            float lb = ldext(lin_b, f32, col);
#pragma unroll
            for (int r = 0; r < 4; r++) {
                int rw = nb + quad * 4 + r;
                if (rw < N_NODES) {
                    float v = out_acc[(size_t)rw * OUT_DIM + col] + j[r] + lb;
                    if (f32) ((float*)d_out)[(size_t)rw * OUT_DIM + col] = v;
                    else ((__hip_bfloat16*)d_out)[(size_t)rw * OUT_DIM + col] = __float2bfloat16(v);
                }
            }
        }
    }
}

extern "C" void kernel_launch(void* const* d_in, const int* in_sizes, int n_in,
                              void* d_out, int out_size, void* d_ws, size_t ws_size,
                              hipStream_t stream) {
    const void* x     = d_in[0];
    const void* W0    = d_in[1];
    const void* Ws    = d_in[2];
    const void* bs    = d_in[3];
    const void* lin_w = d_in[4];
    const void* lin_b = d_in[5];
    const void* ei    = d_in[6];

    size_t off = 0;
    auto alloc = [&](size_t bytes) -> void* {
        void* p = (char*)d_ws + off;
        off += (bytes + 511) & ~(size_t)511;
        return p;
    };
    int*   flags   = (int*)alloc(512);
    float* dis     = (float*)alloc((size_t)(N_NODES + 64) * 4);
    int*   deg     = (int*)alloc((size_t)N_NODES * 4);
    int*   row     = (int*)alloc((size_t)(N_NODES + 1) * 4);
    int*   bsums   = (int*)alloc(128 * 4);
    int*   gcur    = (int*)alloc((size_t)NBUK * 4);
    int*   fifo    = (int*)alloc((size_t)NBUK * BUK_CAP * 4);   // 9.4 MB
    int*   csr_src = (int*)alloc((size_t)N_EDGES * 4);
    __half* t0s = (__half*)alloc((size_t)4 * T0SL4 * 2);
    __half* h   = (__half*)alloc((size_t)(N_NODES + 32) * HID * 2);
    __hip_bfloat16* xbf = (__hip_bfloat16*)alloc((size_t)(N_NODES + 32) * 128 * 2);
    float* out_acc = (float*)alloc((size_t)N_NODES * OUT_DIM * 4);
    float* bsf     = (float*)alloc((size_t)LAYERS * HID * 4);
    unsigned short* wpack = (unsigned short*)alloc((size_t)61440 * 2);

    const int nblkN  = (N_NODES + 255) / 256;
    const int nblkS1 = (N_EDGES + S1_EPB - 1) / S1_EPB;   // 782
    const int nblkMM = (N_NODES + 63) / 64;               // 1563
    const int nblkAG = ((N_NODES + AGG_N - 1) / AGG_N) * 4;  // 782*4 = 3128

    detect_kernel<<<1, 64, 0, stream>>>(x, ei, flags);
    pack_params_kernel<<<80, 256, 0, stream>>>(bs, lin_w, W0, Ws, flags, bsf, wpack);
    convert_x_kernel<<<(N_NODES * 128 / 4) / 256, 256, 0, stream>>>(x, flags, xbf);
    zero_int_kernel<<<1, 256, 0, stream>>>(gcur, NBUK);
    bucket1_kernel<<<nblkS1, 256, 0, stream>>>(ei, flags, gcur, fifo);
    deg_fifo_kernel<<<NBUK, 256, 0, stream>>>(gcur, fifo, deg);
    calc_dis_kernel<<<nblkN, 256, 0, stream>>>(deg, dis);
    scan1_kernel<<<SCAN_NB, 256, 0, stream>>>(deg, row, bsums);
    scan2_kernel<<<1, 128, 0, stream>>>(bsums);
    scan3_kernel<<<nblkN, 256, 0, stream>>>(row, bsums);
    bucket2_kernel<<<NBUK, 256, 0, stream>>>(gcur, fifo, row, csr_src);

    const unsigned short* wJ0 = wpack + 36864;
    for (int l = 0; l < LAYERS; l++) {
        if (l == 0) {
            mm_mfma_kernel<4, 0, true><<<nblkMM, 256, 0, stream>>>(
                x, xbf, flags, wpack, nullptr, dis, t0s, nullptr);
        } else if (l == 1) {
            mm_mfma_kernel<2, 1, false><<<nblkMM, 256, 0, stream>>>(
                h, h, flags, wpack + 8192, wJ0, dis, t0s, out_acc);
        } else {
            mm_mfma_kernel<2, 2, false><<<nblkMM, 256, 0, stream>>>(
                h, h, flags, wpack + 8192 + (size_t)(l - 1) * 4096,
                wJ0 + (size_t)(l - 1) * 3072, dis, t0s, out_acc);
        }
        agg_kernel<<<nblkAG, 256, 0, stream>>>(t0s, row, csr_src, dis,
                                               bsf + (size_t)l * HID, h);
    }
    jk_final_kernel<<<nblkMM, 256, 0, stream>>>(h, wJ0 + (size_t)7 * 3072, out_acc,
                                                lin_b, flags, d_out);
}